// Round 2
// 255.888 us; speedup vs baseline: 1.0132x; 1.0132x over previous
//
#include <hip/hip_runtime.h>
#include <stdint.h>

typedef __bf16 bf16;
typedef __bf16 bf16x4 __attribute__((ext_vector_type(4)));
typedef __bf16 bf16x8 __attribute__((ext_vector_type(8)));
typedef float f32x4 __attribute__((ext_vector_type(4)));
typedef float f32x16 __attribute__((ext_vector_type(16)));
typedef unsigned int uintx2 __attribute__((ext_vector_type(2)));
typedef unsigned int uintx4 __attribute__((ext_vector_type(4)));

#define MFMA16(a, b, c) __builtin_amdgcn_mfma_f32_16x16x32_bf16((a), (b), (c), 0, 0, 0)
#define MFMA32(a, b, c) __builtin_amdgcn_mfma_f32_32x32x16_bf16((a), (b), (c), 0, 0, 0)

// Async global->LDS, 16 B per lane: lane i's 16 B lands at ldsbase + i*16
// (wave-uniform base, m104/m108). Global address is per-lane.
__device__ __forceinline__ void gload16(const bf16* g, bf16* l) {
    __builtin_amdgcn_global_load_lds(
        (const __attribute__((address_space(1))) void*)g,
        (__attribute__((address_space(3))) void*)l, 16, 0, 0);
}

__device__ __forceinline__ float fast_exp2(float x) {
#if __has_builtin(__builtin_amdgcn_exp2f)
    return __builtin_amdgcn_exp2f(x);
#else
    return exp2f(x);
#endif
}

// ---------------------------------------------------------------------------
// fp32 -> bf16 for q,k,v (4M each) and Wq,Wk,Wv,Wo (1M each).
// ---------------------------------------------------------------------------
__global__ __launch_bounds__(256) void cvt_kernel(
    const float* __restrict__ q, const float* __restrict__ k, const float* __restrict__ v,
    const float* __restrict__ wq, const float* __restrict__ wk,
    const float* __restrict__ wv, const float* __restrict__ wo,
    bf16* __restrict__ qb, bf16* __restrict__ kb, bf16* __restrict__ vb,
    bf16* __restrict__ wqb, bf16* __restrict__ wkb, bf16* __restrict__ wvb,
    bf16* __restrict__ wob)
{
    int z = blockIdx.z;
    const float* src; bf16* dst; int n;
    switch (z) {
        case 0:  src = q;  dst = qb;  n = 4194304; break;
        case 1:  src = k;  dst = kb;  n = 4194304; break;
        case 2:  src = v;  dst = vb;  n = 4194304; break;
        case 3:  src = wq; dst = wqb; n = 1048576; break;
        case 4:  src = wk; dst = wkb; n = 1048576; break;
        case 5:  src = wv; dst = wvb; n = 1048576; break;
        default: src = wo; dst = wob; n = 1048576; break;
    }
    int i = (blockIdx.x * 256 + threadIdx.x) * 8;
    if (i >= n) return;
    float4 f0 = *(const float4*)(src + i);
    float4 f1 = *(const float4*)(src + i + 4);
    bf16x8 o;
    o[0] = (bf16)f0.x; o[1] = (bf16)f0.y; o[2] = (bf16)f0.z; o[3] = (bf16)f0.w;
    o[4] = (bf16)f1.x; o[5] = (bf16)f1.y; o[6] = (bf16)f1.z; o[7] = (bf16)f1.w;
    *(bf16x8*)(dst + i) = o;
}

// ---------------------------------------------------------------------------
// mask [2048][2048] int32 -> maskb [2048][32] uint64 via __ballot.
// ---------------------------------------------------------------------------
__global__ __launch_bounds__(256) void maskpack_kernel(
    const int* __restrict__ mask, unsigned long long* __restrict__ maskb)
{
    int gid  = blockIdx.x * 256 + threadIdx.x;
    int word = gid >> 6;
    int lane = gid & 63;
    int row = word >> 5, wc = word & 31;
    int mv = mask[row * 2048 + wc * 64 + lane];
    unsigned long long bits = __ballot(mv != 0);
    if (lane == 0) maskb[word] = bits;
}

// ---------------------------------------------------------------------------
// NT GEMM (bf16): m97 structure (unchanged to isolate the flash change).
// Q epilogue scale folds log2(e) so flash can use raw v_exp_f32 (exp2).
// ---------------------------------------------------------------------------
template <int OUTMODE, int MT>
__global__ __launch_bounds__(256) void gemm_kernel(
    const bf16* __restrict__ A0, const bf16* __restrict__ A1, const bf16* __restrict__ A2,
    const bf16* __restrict__ B0, const bf16* __restrict__ B1, const bf16* __restrict__ B2,
    bf16* __restrict__ C0, bf16* __restrict__ C1, bf16* __restrict__ C2,
    const float* __restrict__ bias, float* __restrict__ outf)
{
    constexpr int MI = (MT == 128) ? 4 : 2;

    const int z = blockIdx.z;
    const bf16* A = (z == 0) ? A0 : (z == 1) ? A1 : A2;
    const bf16* B = (z == 0) ? B0 : (z == 1) ? B1 : B2;

    __shared__ bf16 At[MT * 32];
    __shared__ bf16 Bt[128 * 32];

    const int tid  = threadIdx.x;
    const int lane = tid & 63;
    const int wave = tid >> 6;
    const int quad = lane >> 4;
    const int l16  = lane & 15;
    const int wm = (wave >> 1) * (MT / 2);
    const int wn = (wave & 1) * 64;
    const int m0 = blockIdx.y * MT;
    const int n0 = blockIdx.x * 128;

    const int lrow = lane >> 2;
    const int lcol = (lane & 3) * 8;

    f32x4 acc[MI][4] = {};

    const bf16* Ag = A + (size_t)(m0 + lrow) * 1024 + lcol;
    const bf16* Bg = B + (size_t)(n0 + lrow) * 1024 + lcol;

    for (int k0 = 0; k0 < 1024; k0 += 32) {
        __syncthreads();
        if constexpr (MT == 128) {
#pragma unroll
            for (int j = 0; j < 2; ++j)
                gload16(Ag + (size_t)(wave * 32 + j * 16) * 1024 + k0,
                        At + (wave * 32 + j * 16) * 32);
        } else {
            gload16(Ag + (size_t)(wave * 16) * 1024 + k0, At + (wave * 16) * 32);
        }
#pragma unroll
        for (int j = 0; j < 2; ++j)
            gload16(Bg + (size_t)(wave * 32 + j * 16) * 1024 + k0,
                    Bt + (wave * 32 + j * 16) * 32);
        __syncthreads();

        bf16x8 af[MI], bg[4];
#pragma unroll
        for (int i = 0; i < MI; ++i)
            af[i] = *(const bf16x8*)(At + (wm + i * 16 + l16) * 32 + quad * 8);
#pragma unroll
        for (int j = 0; j < 4; ++j)
            bg[j] = *(const bf16x8*)(Bt + (wn + j * 16 + l16) * 32 + quad * 8);
#pragma unroll
        for (int i = 0; i < MI; ++i)
#pragma unroll
            for (int j = 0; j < 4; ++j)
                acc[i][j] = MFMA16(af[i], bg[j], acc[i][j]);
    }

    if constexpr (OUTMODE == 0) {
        bf16* C = (z == 0) ? C0 : (z == 1) ? C1 : C2;
        // z==0 (Q): (1/sqrt(1024)) * log2(e) so flash's exp2 == exp.
        const float cs = (z == 0) ? 0.0450842200277800f : 1.0f;
#pragma unroll
        for (int i = 0; i < MI; ++i)
#pragma unroll
            for (int j = 0; j < 4; ++j) {
                int row = m0 + wm + i * 16 + quad * 4;
                int col = n0 + wn + j * 16 + l16;
#pragma unroll
                for (int r = 0; r < 4; ++r)
                    C[(row + r) * 1024 + col] = (bf16)(acc[i][j][r] * cs);
            }
    } else {
#pragma unroll
        for (int j = 0; j < 4; ++j) {
            int col = n0 + wn + j * 16 + l16;
            float bj = bias[col];
#pragma unroll
            for (int i = 0; i < MI; ++i) {
                int row = m0 + wm + i * 16 + quad * 4;
#pragma unroll
                for (int r = 0; r < 4; ++r)
                    outf[(row + r) * 1024 + col] = acc[i][j][r] + bj;
            }
        }
    }
}

// ---------------------------------------------------------------------------
// V [b*2048+s][1024] -> Vt [b][h*64+d][s]  (64x64 LDS-tiled transpose)
// ---------------------------------------------------------------------------
__global__ __launch_bounds__(256) void transpose_kernel(const bf16* __restrict__ V,
                                                        bf16* __restrict__ Vt)
{
    __shared__ bf16 t[64][72];
    const int tid = threadIdx.x;
    const int b  = blockIdx.z;
    const int s0 = blockIdx.x * 64;
    const int d0 = blockIdx.y * 64;
#pragma unroll
    for (int c = 0; c < 2; ++c) {
        int qq = c * 256 + tid;
        int row = qq >> 3, col = (qq & 7) * 8;
        *(uint4*)(&t[row][col]) =
            *(const uint4*)(V + (size_t)(b * 2048 + s0 + row) * 1024 + d0 + col);
    }
    __syncthreads();
#pragma unroll
    for (int c = 0; c < 2; ++c) {
        int qq = c * 256 + tid;
        int drow = qq >> 3, scol = (qq & 7) * 8;
        bf16x8 o;
#pragma unroll
        for (int j = 0; j < 8; ++j) o[j] = t[scol + j][drow];
        *(bf16x8*)(Vt + (size_t)(b * 1024 + d0 + drow) * 2048 + s0 + scol) = o;
    }
}

// ---------------------------------------------------------------------------
// Flash attention v7:
//  * In-register P (T12 structure) with __shfl_xor(.,32) exchange (unambiguous
//    semantics; v6's permlane32_swap convention was wrong -> absmax 6e-2).
//    Mapping (re-derived): src lane (l32,hl_s) reg g*4+r holds
//    P[q=l32][key=t*32+4*hl_s+8g+r]. Dest frag pa[2t+kh] on lane (l32,hl_d)
//    needs keys t*32+kh*16+hl_d*8+{0..7}: words 0-1 from src hl_s=0 group
//    g=2kh+hl_d, words 2-3 from src hl_s=1 same group. Each lane sends group
//    2kh+!hl (partner's need), recv = shfl_xor 32, select by hl.
//  * Scalar bf16 casts packed via bf16x4->uintx2 bit_cast (m240: don't
//    hand-write cvt_pk asm).
//  * exp2 path: Q pre-scaled by log2(e)/32 -> one v_exp_f32 per P element.
//  * Double-buffered K/V, ONE barrier per kt: barrier -> stage(next) ->
//    compute(cur). DMA for kt+1 overlaps compute of kt; next barrier's
//    implicit vmcnt(0) is the drain (T3 minimum 2-phase). LDS 32 KB.
// Block = 128 q x 64-key tile of one (b,h); 4 waves x 32 q.
// 32x32 layouts (m74/m101): C/D col=lane&31, row=(reg&3)+8*(reg>>2)+4*(lane>>5);
// A[m=lane&31][k=(lane>>5)*8+j]; B[k=(lane>>5)*8+j][n=lane&31].
// ---------------------------------------------------------------------------
__global__ __launch_bounds__(256) void flash_kernel(
    const bf16* __restrict__ Q, const bf16* __restrict__ K, const bf16* __restrict__ Vt,
    const unsigned long long* __restrict__ maskb, bf16* __restrict__ O)
{
    __shared__ bf16 Kl[2][64 * 64];   // [buf][key][d-chunk swizzled]   2x8 KB
    __shared__ bf16 Vl[2][64 * 64];   // [buf][d][key-chunk swizzled]   2x8 KB

    const int tid  = threadIdx.x;
    const int lane = tid & 63;
    const int wave = tid >> 6;       // q-tile 0..3
    const int l32  = lane & 31;
    const int hl   = lane >> 5;      // 0/1
    const int l7   = lane & 7;
    const int b  = blockIdx.z;
    const int h  = blockIdx.y;
    const int q0 = blockIdx.x * 128;
    const int qt = q0 + wave * 32;   // wave's q rows qt..qt+31

    // Q B-frags: B[k=d(hl*8+j)][n=q(l32)], 4 k-steps of 16
    const bf16* Qb = Q + (size_t)(b * 2048 + qt + l32) * 1024 + h * 64 + hl * 8;
    bf16x8 qf[4];
#pragma unroll
    for (int ks = 0; ks < 4; ++ks) qf[ks] = *(const bf16x8*)(Qb + ks * 16);

    bf16x8 ones;
#pragma unroll
    for (int j = 0; j < 8; ++j) ones[j] = (bf16)1.0f;

    f32x16 acc[2] = {};
    f32x16 lacc = {};

    // DMA staging: wave stages K rows wave*16..+15 and V rows wave*16..+15,
    // 2 calls each (8 rows/call). Lane i -> local row i>>3, LDS chunk i&7,
    // global chunk (i&7)^(i>>3) (row&7 == i>>3 since call bases are %8==0).
    const int dmarow = lane >> 3;
    const int dmacol = (l7 ^ dmarow) * 8;
    const bf16* Kg = K + (size_t)(b * 2048 + wave * 16 + dmarow) * 1024 + h * 64 + dmacol;
    const bf16* Vg = Vt + (size_t)((b * 16 + h) * 64 + wave * 16 + dmarow) * 2048 + dmacol;
    const unsigned long long* Mg = maskb + (size_t)(qt + l32) * 32;

    auto stage = [&](bf16* Kd, bf16* Vd, int kt) {
        gload16(Kg + (size_t)kt * 1024,       Kd + (wave * 16) * 64);
        gload16(Kg + (size_t)(kt + 8) * 1024, Kd + (wave * 16 + 8) * 64);
        gload16(Vg + kt,                      Vd + (wave * 16) * 64);
        gload16(Vg + kt + 8 * 2048,           Vd + (wave * 16 + 8) * 64);
    };

    unsigned long long mw = Mg[0];
    stage(Kl[0], Vl[0], 0);          // prologue: buf 0 <- kt 0

    auto body = [&](const bf16* Kc, const bf16* Vc, bf16* Kn, bf16* Vn, int it) {
        __syncthreads();             // drains buf[cur] DMA; prev frag reads done
        unsigned long long mw_next = 0;
        if (it + 1 < 32) {           // uniform branch
            stage(Kn, Vn, (it + 1) * 64);     // overlaps with compute below
            mw_next = Mg[it + 1];
        }

        // S^T = K Q^T: two 32-key tiles, C[m=key][n=q], then mask+exp2 and
        // in-register repack to PV A-frags.
        bf16x8 pa[4];
#pragma unroll
        for (int t = 0; t < 2; ++t) {
            f32x16 s = {};
#pragma unroll
            for (int ks = 0; ks < 4; ++ks) {
                bf16x8 ka = *(const bf16x8*)(Kc + (t * 32 + l32) * 64 +
                                             (((ks * 2 + hl) ^ l7) * 8));
                s = MFMA32(ka, qf[ks], s);
            }
            // reg g*4+r -> key t*32 + 4*hl + 8*g + r
            unsigned mwt = (unsigned)(mw >> (t * 32 + 4 * hl));
            unsigned W[4][2];
#pragma unroll
            for (int g = 0; g < 4; ++g) {
                bf16x4 pv;
#pragma unroll
                for (int r = 0; r < 4; ++r) {
                    float ev = fast_exp2(s[g * 4 + r]);   // Q pre-scaled log2e/32
                    pv[r] = (mwt & (1u << (8 * g + r))) ? (bf16)ev : (bf16)0.0f;
                }
                uintx2 u = __builtin_bit_cast(uintx2, pv);
                W[g][0] = u[0];
                W[g][1] = u[1];
            }
            // Exchange at lane^32: each lane sends group 2kh+!hl, then
            // lo words = hl ? recv : own-even ; hi words = hl ? own-odd : recv.
#pragma unroll
            for (int kh = 0; kh < 2; ++kh) {
                unsigned s0 = hl ? W[2 * kh][0] : W[2 * kh + 1][0];
                unsigned s1 = hl ? W[2 * kh][1] : W[2 * kh + 1][1];
                unsigned r0 = __shfl_xor(s0, 32, 64);
                unsigned r1 = __shfl_xor(s1, 32, 64);
                uintx4 aw;
                aw[0] = hl ? r0 : W[2 * kh][0];
                aw[1] = hl ? r1 : W[2 * kh][1];
                aw[2] = hl ? W[2 * kh + 1][0] : r0;
                aw[3] = hl ? W[2 * kh + 1][1] : r1;
                pa[t * 2 + kh] = __builtin_bit_cast(bf16x8, aw);
            }
        }

        // PV: A=P (in-register), B=Vt[k=key][n=d] from swizzled Vl
#pragma unroll
        for (int dt = 0; dt < 2; ++dt)
#pragma unroll
            for (int ks = 0; ks < 4; ++ks) {
                bf16x8 vb = *(const bf16x8*)(Vc + (dt * 32 + l32) * 64 +
                                             (((ks * 2 + hl) ^ l7) * 8));
                acc[dt] = MFMA32(pa[ks], vb, acc[dt]);
            }
#pragma unroll
        for (int ks = 0; ks < 4; ++ks)
            lacc = MFMA32(pa[ks], ones, lacc);   // row-sums, all n identical

        mw = mw_next;
    };

    for (int it = 0; it < 32; it += 2) {
        body(Kl[0], Vl[0], Kl[1], Vl[1], it);
        body(Kl[1], Vl[1], Kl[0], Vl[0], it + 1);
    }

    // Epilogue: row q_rel = 4*hl + 8*g + r, col d = dt*32 + l32
    const size_t obase = (size_t)(b * 2048 + qt) * 1024 + h * 64;
#pragma unroll
    for (int g = 0; g < 4; ++g)
#pragma unroll
        for (int r = 0; r < 4; ++r) {
            int qr = 4 * hl + 8 * g + r;
            float inv = 1.0f / lacc[g * 4 + r];
            O[obase + (size_t)qr * 1024 + l32]      = (bf16)(acc[0][g * 4 + r] * inv);
            O[obase + (size_t)qr * 1024 + 32 + l32] = (bf16)(acc[1][g * 4 + r] * inv);
        }
}

// ---------------------------------------------------------------------------
extern "C" void kernel_launch(void* const* d_in, const int* in_sizes, int n_in,
                              void* d_out, int out_size, void* d_ws, size_t ws_size,
                              hipStream_t stream)
{
    const float* q  = (const float*)d_in[0];
    const float* k  = (const float*)d_in[1];
    const float* v  = (const float*)d_in[2];
    const int* mask = (const int*)d_in[3];
    const float* wq = (const float*)d_in[4];
    const float* wk = (const float*)d_in[5];
    const float* wv = (const float*)d_in[6];
    const float* wo = (const float*)d_in[7];
    const float* bo = (const float*)d_in[8];
    float* out = (float*)d_out;

    char* p = (char*)d_ws;
    auto alloc = [&](size_t bytes) {
        char* r = p;
        p += (bytes + 255) & ~(size_t)255;
        return r;
    };
    const size_t SB = (size_t)4096 * 1024 * 2;
    const size_t WB = (size_t)1024 * 1024 * 2;
    bf16* qb  = (bf16*)alloc(SB);
    bf16* kb  = (bf16*)alloc(SB);
    bf16* vb  = (bf16*)alloc(SB);
    bf16* wqb = (bf16*)alloc(WB);
    bf16* wkb = (bf16*)alloc(WB);
    bf16* wvb = (bf16*)alloc(WB);
    bf16* wob = (bf16*)alloc(WB);
    bf16* Qp  = (bf16*)alloc(SB);
    bf16* Kp  = (bf16*)alloc(SB);
    bf16* Vp  = (bf16*)alloc(SB);
    bf16* Vtp = (bf16*)alloc(SB);
    bf16* Ob  = (bf16*)alloc(SB);
    unsigned long long* maskb = (unsigned long long*)alloc(2048 * 32 * 8);

    cvt_kernel<<<dim3(2048, 1, 7), 256, 0, stream>>>(
        q, k, v, wq, wk, wv, wo, qb, kb, vb, wqb, wkb, wvb, wob);

    maskpack_kernel<<<dim3(16384), 256, 0, stream>>>(mask, maskb);

    gemm_kernel<0, 128><<<dim3(8, 32, 3), 256, 0, stream>>>(
        qb, kb, vb, wqb, wkb, wvb, Qp, Kp, Vp, nullptr, nullptr);

    transpose_kernel<<<dim3(32, 16, 2), 256, 0, stream>>>(Vp, Vtp);

    flash_kernel<<<dim3(16, 16, 2), 256, 0, stream>>>(Qp, Kp, Vtp, maskb, Ob);

    gemm_kernel<1, 64><<<dim3(8, 64, 1), 256, 0, stream>>>(
        Ob, nullptr, nullptr, wob, nullptr, nullptr,
        nullptr, nullptr, nullptr, bo, out);
}

// Round 3
// 240.650 us; speedup vs baseline: 1.0774x; 1.0633x over previous
//
#include <hip/hip_runtime.h>
#include <stdint.h>

typedef __bf16 bf16;
typedef __bf16 bf16x4 __attribute__((ext_vector_type(4)));
typedef __bf16 bf16x8 __attribute__((ext_vector_type(8)));
typedef float f32x4 __attribute__((ext_vector_type(4)));
typedef float f32x16 __attribute__((ext_vector_type(16)));
typedef unsigned int uintx2 __attribute__((ext_vector_type(2)));
typedef unsigned int uintx4 __attribute__((ext_vector_type(4)));

#define MFMA16(a, b, c) __builtin_amdgcn_mfma_f32_16x16x32_bf16((a), (b), (c), 0, 0, 0)
#define MFMA32(a, b, c) __builtin_amdgcn_mfma_f32_32x32x16_bf16((a), (b), (c), 0, 0, 0)

// Async global->LDS, 16 B per lane: lane i's 16 B lands at ldsbase + i*16
// (wave-uniform base, m104/m108). Global address is per-lane.
__device__ __forceinline__ void gload16(const bf16* g, bf16* l) {
    __builtin_amdgcn_global_load_lds(
        (const __attribute__((address_space(1))) void*)g,
        (__attribute__((address_space(3))) void*)l, 16, 0, 0);
}

__device__ __forceinline__ float fast_exp2(float x) {
#if __has_builtin(__builtin_amdgcn_exp2f)
    return __builtin_amdgcn_exp2f(x);
#else
    return exp2f(x);
#endif
}

// ---------------------------------------------------------------------------
// fp32 -> bf16 for q,k,v (4M each) and Wq,Wk,Wv,Wo (1M each).
// ---------------------------------------------------------------------------
__global__ __launch_bounds__(256) void cvt_kernel(
    const float* __restrict__ q, const float* __restrict__ k, const float* __restrict__ v,
    const float* __restrict__ wq, const float* __restrict__ wk,
    const float* __restrict__ wv, const float* __restrict__ wo,
    bf16* __restrict__ qb, bf16* __restrict__ kb, bf16* __restrict__ vb,
    bf16* __restrict__ wqb, bf16* __restrict__ wkb, bf16* __restrict__ wvb,
    bf16* __restrict__ wob)
{
    int z = blockIdx.z;
    const float* src; bf16* dst; int n;
    switch (z) {
        case 0:  src = q;  dst = qb;  n = 4194304; break;
        case 1:  src = k;  dst = kb;  n = 4194304; break;
        case 2:  src = v;  dst = vb;  n = 4194304; break;
        case 3:  src = wq; dst = wqb; n = 1048576; break;
        case 4:  src = wk; dst = wkb; n = 1048576; break;
        case 5:  src = wv; dst = wvb; n = 1048576; break;
        default: src = wo; dst = wob; n = 1048576; break;
    }
    int i = (blockIdx.x * 256 + threadIdx.x) * 8;
    if (i >= n) return;
    float4 f0 = *(const float4*)(src + i);
    float4 f1 = *(const float4*)(src + i + 4);
    bf16x8 o;
    o[0] = (bf16)f0.x; o[1] = (bf16)f0.y; o[2] = (bf16)f0.z; o[3] = (bf16)f0.w;
    o[4] = (bf16)f1.x; o[5] = (bf16)f1.y; o[6] = (bf16)f1.z; o[7] = (bf16)f1.w;
    *(bf16x8*)(dst + i) = o;
}

// ---------------------------------------------------------------------------
// mask [2048][2048] int32 -> maskb [2048][32] uint64 via __ballot.
// ---------------------------------------------------------------------------
__global__ __launch_bounds__(256) void maskpack_kernel(
    const int* __restrict__ mask, unsigned long long* __restrict__ maskb)
{
    int gid  = blockIdx.x * 256 + threadIdx.x;
    int word = gid >> 6;
    int lane = gid & 63;
    int row = word >> 5, wc = word & 31;
    int mv = mask[row * 2048 + wc * 64 + lane];
    unsigned long long bits = __ballot(mv != 0);
    if (lane == 0) maskb[word] = bits;
}

// ---------------------------------------------------------------------------
// NT GEMM (bf16): m97 structure (unchanged to isolate the flash change).
// Q epilogue scale folds log2(e) so flash can use raw v_exp_f32 (exp2).
// ---------------------------------------------------------------------------
template <int OUTMODE, int MT>
__global__ __launch_bounds__(256) void gemm_kernel(
    const bf16* __restrict__ A0, const bf16* __restrict__ A1, const bf16* __restrict__ A2,
    const bf16* __restrict__ B0, const bf16* __restrict__ B1, const bf16* __restrict__ B2,
    bf16* __restrict__ C0, bf16* __restrict__ C1, bf16* __restrict__ C2,
    const float* __restrict__ bias, float* __restrict__ outf)
{
    constexpr int MI = (MT == 128) ? 4 : 2;

    const int z = blockIdx.z;
    const bf16* A = (z == 0) ? A0 : (z == 1) ? A1 : A2;
    const bf16* B = (z == 0) ? B0 : (z == 1) ? B1 : B2;

    __shared__ bf16 At[MT * 32];
    __shared__ bf16 Bt[128 * 32];

    const int tid  = threadIdx.x;
    const int lane = tid & 63;
    const int wave = tid >> 6;
    const int quad = lane >> 4;
    const int l16  = lane & 15;
    const int wm = (wave >> 1) * (MT / 2);
    const int wn = (wave & 1) * 64;
    const int m0 = blockIdx.y * MT;
    const int n0 = blockIdx.x * 128;

    const int lrow = lane >> 2;
    const int lcol = (lane & 3) * 8;

    f32x4 acc[MI][4] = {};

    const bf16* Ag = A + (size_t)(m0 + lrow) * 1024 + lcol;
    const bf16* Bg = B + (size_t)(n0 + lrow) * 1024 + lcol;

    for (int k0 = 0; k0 < 1024; k0 += 32) {
        __syncthreads();
        if constexpr (MT == 128) {
#pragma unroll
            for (int j = 0; j < 2; ++j)
                gload16(Ag + (size_t)(wave * 32 + j * 16) * 1024 + k0,
                        At + (wave * 32 + j * 16) * 32);
        } else {
            gload16(Ag + (size_t)(wave * 16) * 1024 + k0, At + (wave * 16) * 32);
        }
#pragma unroll
        for (int j = 0; j < 2; ++j)
            gload16(Bg + (size_t)(wave * 32 + j * 16) * 1024 + k0,
                    Bt + (wave * 32 + j * 16) * 32);
        __syncthreads();

        bf16x8 af[MI], bg[4];
#pragma unroll
        for (int i = 0; i < MI; ++i)
            af[i] = *(const bf16x8*)(At + (wm + i * 16 + l16) * 32 + quad * 8);
#pragma unroll
        for (int j = 0; j < 4; ++j)
            bg[j] = *(const bf16x8*)(Bt + (wn + j * 16 + l16) * 32 + quad * 8);
#pragma unroll
        for (int i = 0; i < MI; ++i)
#pragma unroll
            for (int j = 0; j < 4; ++j)
                acc[i][j] = MFMA16(af[i], bg[j], acc[i][j]);
    }

    if constexpr (OUTMODE == 0) {
        bf16* C = (z == 0) ? C0 : (z == 1) ? C1 : C2;
        // z==0 (Q): (1/sqrt(1024)) * log2(e) so flash's exp2 == exp.
        const float cs = (z == 0) ? 0.0450842200277800f : 1.0f;
#pragma unroll
        for (int i = 0; i < MI; ++i)
#pragma unroll
            for (int j = 0; j < 4; ++j) {
                int row = m0 + wm + i * 16 + quad * 4;
                int col = n0 + wn + j * 16 + l16;
#pragma unroll
                for (int r = 0; r < 4; ++r)
                    C[(row + r) * 1024 + col] = (bf16)(acc[i][j][r] * cs);
            }
    } else {
#pragma unroll
        for (int j = 0; j < 4; ++j) {
            int col = n0 + wn + j * 16 + l16;
            float bj = bias[col];
#pragma unroll
            for (int i = 0; i < MI; ++i) {
                int row = m0 + wm + i * 16 + quad * 4;
#pragma unroll
                for (int r = 0; r < 4; ++r)
                    outf[(row + r) * 1024 + col] = acc[i][j][r] + bj;
            }
        }
    }
}

// ---------------------------------------------------------------------------
// V [b*2048+s][1024] -> Vt [b][h*64+d][s']  (64x64 LDS-tiled transpose).
// s' is PERMUTED: position p holds key swap23(p) (bits 2<->3 within each
// 16-key group). This makes flash's PV B-operand slot order match the
// QK^T C-layout's natural per-lane key order -> no P exchange needed.
// ---------------------------------------------------------------------------
__global__ __launch_bounds__(256) void transpose_kernel(const bf16* __restrict__ V,
                                                        bf16* __restrict__ Vt)
{
    __shared__ bf16 t[64][72];
    const int tid = threadIdx.x;
    const int b  = blockIdx.z;
    const int s0 = blockIdx.x * 64;
    const int d0 = blockIdx.y * 64;
#pragma unroll
    for (int c = 0; c < 2; ++c) {
        int qq = c * 256 + tid;
        int row = qq >> 3, col = (qq & 7) * 8;
        *(uint4*)(&t[row][col]) =
            *(const uint4*)(V + (size_t)(b * 2048 + s0 + row) * 1024 + d0 + col);
    }
    __syncthreads();
#pragma unroll
    for (int c = 0; c < 2; ++c) {
        int qq = c * 256 + tid;
        int drow = qq >> 3, scol = (qq & 7) * 8;
        bf16x8 o;
#pragma unroll
        for (int j = 0; j < 8; ++j) {
            int sidx  = scol + j;
            int sperm = (sidx & ~12) | ((sidx & 4) << 1) | ((sidx & 8) >> 1);
            o[j] = t[sperm][drow];
        }
        *(bf16x8*)(Vt + (size_t)(b * 1024 + d0 + drow) * 2048 + s0 + scol) = o;
    }
}

// ---------------------------------------------------------------------------
// Flash attention v8:
//  * 8-wave (512-thread) split-K blocks: waves 0-3 = keys 0-1023, waves 4-7 =
//    keys 1024-2047, same 128 q rows. 2x waves/SIMD (R2 showed flash is
//    grid-occupancy-limited: 2 waves/SIMD, 30% no-issue). Partial (acc,lacc)
//    combined through LDS at the end (aliased over K/V buffers, one-time).
//  * NO P exchange: Vt is key-permuted (swap23) so the PV B-operand consumes
//    keys in the QK^T C-layout's natural per-lane order. pa = bit_cast of the
//    packed exp results. (Removes 8 ds_bpermute + 16 selects + lgkm stalls.)
//    Slot check: A slot j of frag 2t+kh = key t*32+16kh+8*(j>>2)+4hl+(j&3);
//    permuted-Vt B slot j = swap23(ks*16+8hl+j) = same. Ones-MFMA row-sum and
//    masking are slot-permutation-invariant.
//  * exp2 path: Q pre-scaled by log2(e)/32 -> one v_exp_f32 per P element.
//  * Double-buffered K/V per half, ONE barrier per kt: barrier -> stage(next)
//    -> compute(cur); next barrier's implicit vmcnt(0) drains. LDS 64 KB.
// 32x32 layouts (m74/m101): C/D col=lane&31, row=(reg&3)+8*(reg>>2)+4*(lane>>5);
// A[m=lane&31][k=(lane>>5)*8+j]; B[k=(lane>>5)*8+j][n=lane&31].
// ---------------------------------------------------------------------------
__global__ __launch_bounds__(512, 4) void flash_kernel(
    const bf16* __restrict__ Q, const bf16* __restrict__ K, const bf16* __restrict__ Vt,
    const unsigned long long* __restrict__ maskb, bf16* __restrict__ O)
{
    __shared__ char smem[65536];     // [half][K0|K1|V0|V1] 4x8KB each; combine alias

    const int tid  = threadIdx.x;
    const int lane = tid & 63;
    const int wave = tid >> 6;       // 0..7
    const int half = wave >> 2;      // key half 0/1
    const int w4   = wave & 3;       // q-subtile 0..3
    const int l32  = lane & 31;
    const int hl   = lane >> 5;      // 0/1
    const int l7   = lane & 7;
    const int b  = blockIdx.z;
    const int h  = blockIdx.y;
    const int q0 = blockIdx.x * 128;
    const int qt = q0 + w4 * 32;     // wave's q rows qt..qt+31

    bf16* hbase = (bf16*)smem + half * 16384;
    bf16* K0 = hbase;
    bf16* K1 = hbase + 4096;
    bf16* V0 = hbase + 8192;
    bf16* V1 = hbase + 12288;

    // Q B-frags: B[k=d(hl*8+j)][n=q(l32)], 4 k-steps of 16
    const bf16* Qb = Q + (size_t)(b * 2048 + qt + l32) * 1024 + h * 64 + hl * 8;
    bf16x8 qf[4];
#pragma unroll
    for (int ks = 0; ks < 4; ++ks) qf[ks] = *(const bf16x8*)(Qb + ks * 16);

    bf16x8 ones;
#pragma unroll
    for (int j = 0; j < 8; ++j) ones[j] = (bf16)1.0f;

    f32x16 acc[2] = {};
    f32x16 lacc = {};

    // DMA staging: each wave stages K rows w4*16..+15 and V rows w4*16..+15 of
    // its half's tile, 2 calls each (8 rows/call). Lane i -> local row i>>3,
    // LDS chunk i&7, global chunk (i&7)^(i>>3).
    const int dmarow = lane >> 3;
    const int dmacol = (l7 ^ dmarow) * 8;
    const bf16* Kg = K + (size_t)(b * 2048 + w4 * 16 + dmarow) * 1024 + h * 64 + dmacol;
    const bf16* Vg = Vt + (size_t)((b * 16 + h) * 64 + w4 * 16 + dmarow) * 2048 + dmacol;
    const unsigned long long* Mg = maskb + (size_t)(qt + l32) * 32 + half * 16;
    const int kbase = half * 1024;

    auto stage = [&](bf16* Kd, bf16* Vd, int ktAbs) {
        gload16(Kg + (size_t)ktAbs * 1024,       Kd + (w4 * 16) * 64);
        gload16(Kg + (size_t)(ktAbs + 8) * 1024, Kd + (w4 * 16 + 8) * 64);
        gload16(Vg + ktAbs,                      Vd + (w4 * 16) * 64);
        gload16(Vg + ktAbs + 8 * 2048,           Vd + (w4 * 16 + 8) * 64);
    };

    unsigned long long mw = Mg[0];
    stage(K0, V0, kbase);            // prologue: buf 0 <- first tile of half

    auto body = [&](const bf16* Kc, const bf16* Vc, bf16* Kn, bf16* Vn, int it) {
        __syncthreads();             // drains buf[cur] DMA; prev frag reads done
        unsigned long long mw_next = 0;
        if (it + 1 < 16) {           // uniform branch
            stage(Kn, Vn, kbase + (it + 1) * 64);   // overlaps compute below
            mw_next = Mg[it + 1];
        }

        // S^T = K Q^T: two 32-key tiles, C[m=key][n=q], then mask+exp2;
        // pa frags are direct bit_casts (permuted-Vt matches slot order).
        bf16x8 pa[4];
#pragma unroll
        for (int t = 0; t < 2; ++t) {
            f32x16 s = {};
#pragma unroll
            for (int ks = 0; ks < 4; ++ks) {
                bf16x8 ka = *(const bf16x8*)(Kc + (t * 32 + l32) * 64 +
                                             (((ks * 2 + hl) ^ l7) * 8));
                s = MFMA32(ka, qf[ks], s);
            }
            // reg g*4+r -> key t*32 + 4*hl + 8*g + r
            unsigned mwt = (unsigned)(mw >> (t * 32 + 4 * hl));
            unsigned W[4][2];
#pragma unroll
            for (int g = 0; g < 4; ++g) {
                bf16x4 pv;
#pragma unroll
                for (int r = 0; r < 4; ++r) {
                    float ev = fast_exp2(s[g * 4 + r]);   // Q pre-scaled log2e/32
                    pv[r] = (mwt & (1u << (8 * g + r))) ? (bf16)ev : (bf16)0.0f;
                }
                uintx2 u = __builtin_bit_cast(uintx2, pv);
                W[g][0] = u[0];
                W[g][1] = u[1];
            }
#pragma unroll
            for (int kh = 0; kh < 2; ++kh) {
                uintx4 aw = { W[2 * kh][0], W[2 * kh][1],
                              W[2 * kh + 1][0], W[2 * kh + 1][1] };
                pa[t * 2 + kh] = __builtin_bit_cast(bf16x8, aw);
            }
        }

        // PV: A=P (in-register), B=V[key-permuted][d] from swizzled Vl
#pragma unroll
        for (int dt = 0; dt < 2; ++dt)
#pragma unroll
            for (int ks = 0; ks < 4; ++ks) {
                bf16x8 vb = *(const bf16x8*)(Vc + (dt * 32 + l32) * 64 +
                                             (((ks * 2 + hl) ^ l7) * 8));
                acc[dt] = MFMA32(pa[ks], vb, acc[dt]);
            }
#pragma unroll
        for (int ks = 0; ks < 4; ++ks)
            lacc = MFMA32(pa[ks], ones, lacc);   // row-sums, all n identical

        mw = mw_next;
    };

    for (int it = 0; it < 16; it += 2) {
        body(K0, V0, K1, V1, it);
        body(K1, V1, K0, V0, it + 1);
    }

    // ---- combine halves through LDS (aliased over K/V buffers) ----
    __syncthreads();                 // all compute done; smem reusable
    float* cb = (float*)smem;        // 12 quads x 256 lanes x 16 B = 48 KB
    float* ex = cb + (w4 * 64 + lane) * 4;   // coalesced: lanes contiguous
    if (half == 1) {
#pragma unroll
        for (int i = 0; i < 4; ++i) {
            f32x4 t0, t1, t2;
#pragma unroll
            for (int j = 0; j < 4; ++j) {
                t0[j] = acc[0][i * 4 + j];
                t1[j] = acc[1][i * 4 + j];
                t2[j] = lacc[i * 4 + j];
            }
            *(f32x4*)(ex + (i + 0) * 1024) = t0;
            *(f32x4*)(ex + (i + 4) * 1024) = t1;
            *(f32x4*)(ex + (i + 8) * 1024) = t2;
        }
    }
    __syncthreads();
    if (half == 0) {
#pragma unroll
        for (int i = 0; i < 4; ++i) {
            f32x4 t0 = *(const f32x4*)(ex + (i + 0) * 1024);
            f32x4 t1 = *(const f32x4*)(ex + (i + 4) * 1024);
            f32x4 t2 = *(const f32x4*)(ex + (i + 8) * 1024);
#pragma unroll
            for (int j = 0; j < 4; ++j) {
                acc[0][i * 4 + j] += t0[j];
                acc[1][i * 4 + j] += t1[j];
                lacc[i * 4 + j]   += t2[j];
            }
        }

        // Epilogue: row q_rel = 4*hl + 8*g + r, col d = dt*32 + l32
        const size_t obase = (size_t)(b * 2048 + qt) * 1024 + h * 64;
#pragma unroll
        for (int g = 0; g < 4; ++g)
#pragma unroll
            for (int r = 0; r < 4; ++r) {
                int qr = 4 * hl + 8 * g + r;
                float inv = 1.0f / lacc[g * 4 + r];
                O[obase + (size_t)qr * 1024 + l32]      = (bf16)(acc[0][g * 4 + r] * inv);
                O[obase + (size_t)qr * 1024 + 32 + l32] = (bf16)(acc[1][g * 4 + r] * inv);
            }
    }
}

// ---------------------------------------------------------------------------
extern "C" void kernel_launch(void* const* d_in, const int* in_sizes, int n_in,
                              void* d_out, int out_size, void* d_ws, size_t ws_size,
                              hipStream_t stream)
{
    const float* q  = (const float*)d_in[0];
    const float* k  = (const float*)d_in[1];
    const float* v  = (const float*)d_in[2];
    const int* mask = (const int*)d_in[3];
    const float* wq = (const float*)d_in[4];
    const float* wk = (const float*)d_in[5];
    const float* wv = (const float*)d_in[6];
    const float* wo = (const float*)d_in[7];
    const float* bo = (const float*)d_in[8];
    float* out = (float*)d_out;

    char* p = (char*)d_ws;
    auto alloc = [&](size_t bytes) {
        char* r = p;
        p += (bytes + 255) & ~(size_t)255;
        return r;
    };
    const size_t SB = (size_t)4096 * 1024 * 2;
    const size_t WB = (size_t)1024 * 1024 * 2;
    bf16* qb  = (bf16*)alloc(SB);
    bf16* kb  = (bf16*)alloc(SB);
    bf16* vb  = (bf16*)alloc(SB);
    bf16* wqb = (bf16*)alloc(WB);
    bf16* wkb = (bf16*)alloc(WB);
    bf16* wvb = (bf16*)alloc(WB);
    bf16* wob = (bf16*)alloc(WB);
    bf16* Qp  = (bf16*)alloc(SB);
    bf16* Kp  = (bf16*)alloc(SB);
    bf16* Vp  = (bf16*)alloc(SB);
    bf16* Vtp = (bf16*)alloc(SB);
    bf16* Ob  = (bf16*)alloc(SB);
    unsigned long long* maskb = (unsigned long long*)alloc(2048 * 32 * 8);

    cvt_kernel<<<dim3(2048, 1, 7), 256, 0, stream>>>(
        q, k, v, wq, wk, wv, wo, qb, kb, vb, wqb, wkb, wvb, wob);

    maskpack_kernel<<<dim3(16384), 256, 0, stream>>>(mask, maskb);

    gemm_kernel<0, 128><<<dim3(8, 32, 3), 256, 0, stream>>>(
        qb, kb, vb, wqb, wkb, wvb, Qp, Kp, Vp, nullptr, nullptr);

    transpose_kernel<<<dim3(32, 16, 2), 256, 0, stream>>>(Vp, Vtp);

    flash_kernel<<<dim3(16, 16, 2), 512, 0, stream>>>(Qp, Kp, Vtp, maskb, Ob);

    gemm_kernel<1, 64><<<dim3(8, 64, 1), 256, 0, stream>>>(
        Ob, nullptr, nullptr, wob, nullptr, nullptr,
        nullptr, nullptr, nullptr, bo, out);
}

// Round 4
// 232.983 us; speedup vs baseline: 1.1128x; 1.0329x over previous
//
#include <hip/hip_runtime.h>
#include <stdint.h>

typedef __bf16 bf16;
typedef __bf16 bf16x4 __attribute__((ext_vector_type(4)));
typedef __bf16 bf16x8 __attribute__((ext_vector_type(8)));
typedef float f32x4 __attribute__((ext_vector_type(4)));
typedef float f32x16 __attribute__((ext_vector_type(16)));
typedef unsigned int uintx2 __attribute__((ext_vector_type(2)));
typedef unsigned int uintx4 __attribute__((ext_vector_type(4)));

#define MFMA16(a, b, c) __builtin_amdgcn_mfma_f32_16x16x32_bf16((a), (b), (c), 0, 0, 0)
#define MFMA32(a, b, c) __builtin_amdgcn_mfma_f32_32x32x16_bf16((a), (b), (c), 0, 0, 0)

// Async global->LDS, 16 B per lane: lane i's 16 B lands at ldsbase + i*16
// (wave-uniform base, m104/m108). Global address is per-lane.
__device__ __forceinline__ void gload16(const bf16* g, bf16* l) {
    __builtin_amdgcn_global_load_lds(
        (const __attribute__((address_space(1))) void*)g,
        (__attribute__((address_space(3))) void*)l, 16, 0, 0);
}

__device__ __forceinline__ float fast_exp2(float x) {
#if __has_builtin(__builtin_amdgcn_exp2f)
    return __builtin_amdgcn_exp2f(x);
#else
    return exp2f(x);
#endif
}

// ---------------------------------------------------------------------------
// fp32 -> bf16 for q,k,v (4M each) and Wq,Wk,Wv,Wo (1M each); z==7 packs the
// mask [2048][2048] int32 -> maskb [2048][32] uint64 via __ballot (linear:
// word*64+lane == gid).
// ---------------------------------------------------------------------------
__global__ __launch_bounds__(256) void cvt_kernel(
    const float* __restrict__ q, const float* __restrict__ k, const float* __restrict__ v,
    const float* __restrict__ wq, const float* __restrict__ wk,
    const float* __restrict__ wv, const float* __restrict__ wo,
    const int* __restrict__ mask,
    bf16* __restrict__ qb, bf16* __restrict__ kb, bf16* __restrict__ vb,
    bf16* __restrict__ wqb, bf16* __restrict__ wkb, bf16* __restrict__ wvb,
    bf16* __restrict__ wob, unsigned long long* __restrict__ maskb)
{
    int z = blockIdx.z;
    if (z == 7) {
#pragma unroll
        for (int it = 0; it < 8; ++it) {
            int gid  = it * 524288 + blockIdx.x * 256 + threadIdx.x;
            int lane = gid & 63;
            int mv = mask[gid];
            unsigned long long bits = __ballot(mv != 0);
            if (lane == 0) maskb[gid >> 6] = bits;
        }
        return;
    }
    const float* src; bf16* dst; int n;
    switch (z) {
        case 0:  src = q;  dst = qb;  n = 4194304; break;
        case 1:  src = k;  dst = kb;  n = 4194304; break;
        case 2:  src = v;  dst = vb;  n = 4194304; break;
        case 3:  src = wq; dst = wqb; n = 1048576; break;
        case 4:  src = wk; dst = wkb; n = 1048576; break;
        case 5:  src = wv; dst = wvb; n = 1048576; break;
        default: src = wo; dst = wob; n = 1048576; break;
    }
    int i = (blockIdx.x * 256 + threadIdx.x) * 8;
    if (i >= n) return;
    float4 f0 = *(const float4*)(src + i);
    float4 f1 = *(const float4*)(src + i + 4);
    bf16x8 o;
    o[0] = (bf16)f0.x; o[1] = (bf16)f0.y; o[2] = (bf16)f0.z; o[3] = (bf16)f0.w;
    o[4] = (bf16)f1.x; o[5] = (bf16)f1.y; o[6] = (bf16)f1.z; o[7] = (bf16)f1.w;
    *(bf16x8*)(dst + i) = o;
}

// ---------------------------------------------------------------------------
// NT GEMM (bf16): m97 K-loop (untouched).
// z==0 (Q) epilogue folds (1/sqrt(1024))*log2(e) so flash uses raw exp2.
// z==2 (V) epilogue writes Vt DIRECTLY: [b][h*64+d][s'] with s' key-permuted
// (swap bits 2<->3 within each 16-group), via a 34.8 KB LDS transpose tile.
// This replaces the separate transpose kernel. Derivation: acc value at
// (s_loc = wm+i*16+quad*4+r, e_loc = wn+j*16+l16) stores to
// T[e_loc][wm+i*16+qswap*4+r] where qswap = quad with its 2 bits swapped
// (sperm swaps bits 2,3 of s_loc; r = bits 0,1 unaffected). Then
// T[e][p] = V[sperm(p)][e] and row-wise writeout gives
// Vt[e][s0+p] = V[s0+sperm(p)][e], matching flash's B-slot order.
// ---------------------------------------------------------------------------
template <int OUTMODE, int MT>
__global__ __launch_bounds__(256) void gemm_kernel(
    const bf16* __restrict__ A0, const bf16* __restrict__ A1, const bf16* __restrict__ A2,
    const bf16* __restrict__ B0, const bf16* __restrict__ B1, const bf16* __restrict__ B2,
    bf16* __restrict__ C0, bf16* __restrict__ C1, bf16* __restrict__ Vt,
    const float* __restrict__ bias, float* __restrict__ outf)
{
    constexpr int MI = (MT == 128) ? 4 : 2;
    constexpr int SMEM = (OUTMODE == 0 && MT == 128) ? (128 * 136) : (MT * 32 + 128 * 32);
    __shared__ bf16 smem[SMEM];
    bf16* At = smem;
    bf16* Bt = smem + MT * 32;

    const int z = blockIdx.z;
    const bf16* A = (z == 0) ? A0 : (z == 1) ? A1 : A2;
    const bf16* B = (z == 0) ? B0 : (z == 1) ? B1 : B2;

    const int tid  = threadIdx.x;
    const int lane = tid & 63;
    const int wave = tid >> 6;
    const int quad = lane >> 4;
    const int l16  = lane & 15;
    const int wm = (wave >> 1) * (MT / 2);
    const int wn = (wave & 1) * 64;
    const int m0 = blockIdx.y * MT;
    const int n0 = blockIdx.x * 128;

    const int lrow = lane >> 2;
    const int lcol = (lane & 3) * 8;

    f32x4 acc[MI][4] = {};

    const bf16* Ag = A + (size_t)(m0 + lrow) * 1024 + lcol;
    const bf16* Bg = B + (size_t)(n0 + lrow) * 1024 + lcol;

    for (int k0 = 0; k0 < 1024; k0 += 32) {
        __syncthreads();
        if constexpr (MT == 128) {
#pragma unroll
            for (int j = 0; j < 2; ++j)
                gload16(Ag + (size_t)(wave * 32 + j * 16) * 1024 + k0,
                        At + (wave * 32 + j * 16) * 32);
        } else {
            gload16(Ag + (size_t)(wave * 16) * 1024 + k0, At + (wave * 16) * 32);
        }
#pragma unroll
        for (int j = 0; j < 2; ++j)
            gload16(Bg + (size_t)(wave * 32 + j * 16) * 1024 + k0,
                    Bt + (wave * 32 + j * 16) * 32);
        __syncthreads();

        bf16x8 af[MI], bg[4];
#pragma unroll
        for (int i = 0; i < MI; ++i)
            af[i] = *(const bf16x8*)(At + (wm + i * 16 + l16) * 32 + quad * 8);
#pragma unroll
        for (int j = 0; j < 4; ++j)
            bg[j] = *(const bf16x8*)(Bt + (wn + j * 16 + l16) * 32 + quad * 8);
#pragma unroll
        for (int i = 0; i < MI; ++i)
#pragma unroll
            for (int j = 0; j < 4; ++j)
                acc[i][j] = MFMA16(af[i], bg[j], acc[i][j]);
    }

    if constexpr (OUTMODE == 0) {
        if (MT == 128 && z == 2) {
            // ---- fused V-transpose epilogue ----
            __syncthreads();                       // frag reads of smem done
            const int qsw = ((quad & 1) << 1) | (quad >> 1);
#pragma unroll
            for (int i = 0; i < MI; ++i)
#pragma unroll
                for (int j = 0; j < 4; ++j) {
                    int e  = wn + j * 16 + l16;
                    int sp = wm + i * 16 + qsw * 4;
                    bf16x4 v4;
#pragma unroll
                    for (int r = 0; r < 4; ++r) v4[r] = (bf16)acc[i][j][r];
                    *(bf16x4*)(smem + e * 136 + sp) = v4;
                }
            __syncthreads();
            const int bq = m0 >> 11;
            const int srow = m0 & 2047;
#pragma unroll
            for (int c = 0; c < 2; ++c) {
                int idx = c * 256 + tid;
                int e = idx >> 2, sc = (idx & 3) * 32;
                bf16* dst = Vt + (size_t)(bq * 1024 + n0 + e) * 2048 + srow + sc;
#pragma unroll
                for (int kk = 0; kk < 4; ++kk)
                    *(bf16x8*)(dst + kk * 8) =
                        *(const bf16x8*)(smem + e * 136 + sc + kk * 8);
            }
            return;
        }
        bf16* C = (z == 0) ? C0 : C1;
        // z==0 (Q): (1/sqrt(1024)) * log2(e) so flash's exp2 == exp.
        const float cs = (z == 0) ? 0.0450842200277800f : 1.0f;
#pragma unroll
        for (int i = 0; i < MI; ++i)
#pragma unroll
            for (int j = 0; j < 4; ++j) {
                int row = m0 + wm + i * 16 + quad * 4;
                int col = n0 + wn + j * 16 + l16;
#pragma unroll
                for (int r = 0; r < 4; ++r)
                    C[(row + r) * 1024 + col] = (bf16)(acc[i][j][r] * cs);
            }
    } else {
#pragma unroll
        for (int j = 0; j < 4; ++j) {
            int col = n0 + wn + j * 16 + l16;
            float bj = bias[col];
#pragma unroll
            for (int i = 0; i < MI; ++i) {
                int row = m0 + wm + i * 16 + quad * 4;
#pragma unroll
                for (int r = 0; r < 4; ++r)
                    outf[(row + r) * 1024 + col] = acc[i][j][r] + bj;
            }
        }
    }
}

// ---------------------------------------------------------------------------
// Flash attention v9 (= v8 + XCD remap + setprio):
//  * 8-wave (512-thread) split-K blocks: waves 0-3 = keys 0-1023, waves 4-7 =
//    keys 1024-2047, same 128 q rows. Partial (acc,lacc) combined through LDS.
//  * T1 XCD remap: all 16 q-tile blocks of one (b,h) land on ONE XCD so K/V
//    is fetched once per XCD (was round-robin -> 70 MB fetch vs ~25 ideal).
//    Bijective: 512 blocks = 8 xcd x 4 bh x 16 qtile.
//  * T5: s_setprio(1) around the MFMA clusters (8-wave schedule has wave
//    role diversity -> scheduler can favor MFMA-entering waves).
//  * NO P exchange: Vt is key-permuted (swap23) so the PV B-operand consumes
//    keys in the QK^T C-layout's natural per-lane order.
//  * exp2 path: Q pre-scaled by log2(e)/32 -> one v_exp_f32 per P element.
//  * Double-buffered K/V per half, ONE barrier per kt.
// 32x32 layouts (m74/m101): C/D col=lane&31, row=(reg&3)+8*(reg>>2)+4*(lane>>5);
// A[m=lane&31][k=(lane>>5)*8+j]; B[k=(lane>>5)*8+j][n=lane&31].
// ---------------------------------------------------------------------------
__global__ __launch_bounds__(512, 4) void flash_kernel(
    const bf16* __restrict__ Q, const bf16* __restrict__ K, const bf16* __restrict__ Vt,
    const unsigned long long* __restrict__ maskb, bf16* __restrict__ O)
{
    __shared__ char smem[65536];     // [half][K0|K1|V0|V1] 4x8KB each; combine alias

    const int tid  = threadIdx.x;
    const int lane = tid & 63;
    const int wave = tid >> 6;       // 0..7
    const int half = wave >> 2;      // key half 0/1
    const int w4   = wave & 3;       // q-subtile 0..3
    const int l32  = lane & 31;
    const int hl   = lane >> 5;      // 0/1
    const int l7   = lane & 7;

    // XCD-aware remap: flat -> (xcd, bh_local, qtile)
    const int flat = blockIdx.x + 16 * (blockIdx.y + 16 * blockIdx.z);
    const int xcd  = flat & 7;
    const int slot = flat >> 3;          // 0..63
    const int bh   = xcd * 4 + (slot >> 4);
    const int h  = bh & 15;
    const int b  = bh >> 4;
    const int q0 = (slot & 15) * 128;
    const int qt = q0 + w4 * 32;     // wave's q rows qt..qt+31

    bf16* hbase = (bf16*)smem + half * 16384;
    bf16* K0 = hbase;
    bf16* K1 = hbase + 4096;
    bf16* V0 = hbase + 8192;
    bf16* V1 = hbase + 12288;

    // Q B-frags: B[k=d(hl*8+j)][n=q(l32)], 4 k-steps of 16
    const bf16* Qb = Q + (size_t)(b * 2048 + qt + l32) * 1024 + h * 64 + hl * 8;
    bf16x8 qf[4];
#pragma unroll
    for (int ks = 0; ks < 4; ++ks) qf[ks] = *(const bf16x8*)(Qb + ks * 16);

    bf16x8 ones;
#pragma unroll
    for (int j = 0; j < 8; ++j) ones[j] = (bf16)1.0f;

    f32x16 acc[2] = {};
    f32x16 lacc = {};

    // DMA staging: each wave stages K rows w4*16..+15 and V rows w4*16..+15 of
    // its half's tile, 2 calls each (8 rows/call). Lane i -> local row i>>3,
    // LDS chunk i&7, global chunk (i&7)^(i>>3).
    const int dmarow = lane >> 3;
    const int dmacol = (l7 ^ dmarow) * 8;
    const bf16* Kg = K + (size_t)(b * 2048 + w4 * 16 + dmarow) * 1024 + h * 64 + dmacol;
    const bf16* Vg = Vt + (size_t)((b * 16 + h) * 64 + w4 * 16 + dmarow) * 2048 + dmacol;
    const unsigned long long* Mg = maskb + (size_t)(qt + l32) * 32 + half * 16;
    const int kbase = half * 1024;

    auto stage = [&](bf16* Kd, bf16* Vd, int ktAbs) {
        gload16(Kg + (size_t)ktAbs * 1024,       Kd + (w4 * 16) * 64);
        gload16(Kg + (size_t)(ktAbs + 8) * 1024, Kd + (w4 * 16 + 8) * 64);
        gload16(Vg + ktAbs,                      Vd + (w4 * 16) * 64);
        gload16(Vg + ktAbs + 8 * 2048,           Vd + (w4 * 16 + 8) * 64);
    };

    unsigned long long mw = Mg[0];
    stage(K0, V0, kbase);            // prologue: buf 0 <- first tile of half

    auto body = [&](const bf16* Kc, const bf16* Vc, bf16* Kn, bf16* Vn, int it) {
        __syncthreads();             // drains buf[cur] DMA; prev frag reads done
        unsigned long long mw_next = 0;
        if (it + 1 < 16) {           // uniform branch
            stage(Kn, Vn, kbase + (it + 1) * 64);   // overlaps compute below
            mw_next = Mg[it + 1];
        }

        // S^T = K Q^T: two 32-key tiles, C[m=key][n=q], then mask+exp2;
        // pa frags are direct bit_casts (permuted-Vt matches slot order).
        bf16x8 pa[4];
#pragma unroll
        for (int t = 0; t < 2; ++t) {
            f32x16 s = {};
            __builtin_amdgcn_s_setprio(1);
#pragma unroll
            for (int ks = 0; ks < 4; ++ks) {
                bf16x8 ka = *(const bf16x8*)(Kc + (t * 32 + l32) * 64 +
                                             (((ks * 2 + hl) ^ l7) * 8));
                s = MFMA32(ka, qf[ks], s);
            }
            __builtin_amdgcn_s_setprio(0);
            // reg g*4+r -> key t*32 + 4*hl + 8*g + r
            unsigned mwt = (unsigned)(mw >> (t * 32 + 4 * hl));
            unsigned W[4][2];
#pragma unroll
            for (int g = 0; g < 4; ++g) {
                bf16x4 pv;
#pragma unroll
                for (int r = 0; r < 4; ++r) {
                    float ev = fast_exp2(s[g * 4 + r]);   // Q pre-scaled log2e/32
                    pv[r] = (mwt & (1u << (8 * g + r))) ? (bf16)ev : (bf16)0.0f;
                }
                uintx2 u = __builtin_bit_cast(uintx2, pv);
                W[g][0] = u[0];
                W[g][1] = u[1];
            }
#pragma unroll
            for (int kh = 0; kh < 2; ++kh) {
                uintx4 aw = { W[2 * kh][0], W[2 * kh][1],
                              W[2 * kh + 1][0], W[2 * kh + 1][1] };
                pa[t * 2 + kh] = __builtin_bit_cast(bf16x8, aw);
            }
        }

        // PV: A=P (in-register), B=V[key-permuted][d] from swizzled Vl
        __builtin_amdgcn_s_setprio(1);
#pragma unroll
        for (int dt = 0; dt < 2; ++dt)
#pragma unroll
            for (int ks = 0; ks < 4; ++ks) {
                bf16x8 vb = *(const bf16x8*)(Vc + (dt * 32 + l32) * 64 +
                                             (((ks * 2 + hl) ^ l7) * 8));
                acc[dt] = MFMA32(pa[ks], vb, acc[dt]);
            }
#pragma unroll
        for (int ks = 0; ks < 4; ++ks)
            lacc = MFMA32(pa[ks], ones, lacc);   // row-sums, all n identical
        __builtin_amdgcn_s_setprio(0);

        mw = mw_next;
    };

    for (int it = 0; it < 16; it += 2) {
        body(K0, V0, K1, V1, it);
        body(K1, V1, K0, V0, it + 1);
    }

    // ---- combine halves through LDS (aliased over K/V buffers) ----
    __syncthreads();                 // all compute done; smem reusable
    float* cb = (float*)smem;        // 12 quads x 256 lanes x 16 B = 48 KB
    float* ex = cb + (w4 * 64 + lane) * 4;   // coalesced: lanes contiguous
    if (half == 1) {
#pragma unroll
        for (int i = 0; i < 4; ++i) {
            f32x4 t0, t1, t2;
#pragma unroll
            for (int j = 0; j < 4; ++j) {
                t0[j] = acc[0][i * 4 + j];
                t1[j] = acc[1][i * 4 + j];
                t2[j] = lacc[i * 4 + j];
            }
            *(f32x4*)(ex + (i + 0) * 1024) = t0;
            *(f32x4*)(ex + (i + 4) * 1024) = t1;
            *(f32x4*)(ex + (i + 8) * 1024) = t2;
        }
    }
    __syncthreads();
    if (half == 0) {
#pragma unroll
        for (int i = 0; i < 4; ++i) {
            f32x4 t0 = *(const f32x4*)(ex + (i + 0) * 1024);
            f32x4 t1 = *(const f32x4*)(ex + (i + 4) * 1024);
            f32x4 t2 = *(const f32x4*)(ex + (i + 8) * 1024);
#pragma unroll
            for (int j = 0; j < 4; ++j) {
                acc[0][i * 4 + j] += t0[j];
                acc[1][i * 4 + j] += t1[j];
                lacc[i * 4 + j]   += t2[j];
            }
        }

        // Epilogue: row q_rel = 4*hl + 8*g + r, col d = dt*32 + l32
        const size_t obase = (size_t)(b * 2048 + qt) * 1024 + h * 64;
#pragma unroll
        for (int g = 0; g < 4; ++g)
#pragma unroll
            for (int r = 0; r < 4; ++r) {
                int qr = 4 * hl + 8 * g + r;
                float inv = 1.0f / lacc[g * 4 + r];
                O[obase + (size_t)qr * 1024 + l32]      = (bf16)(acc[0][g * 4 + r] * inv);
                O[obase + (size_t)qr * 1024 + 32 + l32] = (bf16)(acc[1][g * 4 + r] * inv);
            }
    }
}

// ---------------------------------------------------------------------------
extern "C" void kernel_launch(void* const* d_in, const int* in_sizes, int n_in,
                              void* d_out, int out_size, void* d_ws, size_t ws_size,
                              hipStream_t stream)
{
    const float* q  = (const float*)d_in[0];
    const float* k  = (const float*)d_in[1];
    const float* v  = (const float*)d_in[2];
    const int* mask = (const int*)d_in[3];
    const float* wq = (const float*)d_in[4];
    const float* wk = (const float*)d_in[5];
    const float* wv = (const float*)d_in[6];
    const float* wo = (const float*)d_in[7];
    const float* bo = (const float*)d_in[8];
    float* out = (float*)d_out;

    char* p = (char*)d_ws;
    auto alloc = [&](size_t bytes) {
        char* r = p;
        p += (bytes + 255) & ~(size_t)255;
        return r;
    };
    const size_t SB = (size_t)4096 * 1024 * 2;
    const size_t WB = (size_t)1024 * 1024 * 2;
    bf16* qb  = (bf16*)alloc(SB);
    bf16* kb  = (bf16*)alloc(SB);
    bf16* vb  = (bf16*)alloc(SB);
    bf16* wqb = (bf16*)alloc(WB);
    bf16* wkb = (bf16*)alloc(WB);
    bf16* wvb = (bf16*)alloc(WB);
    bf16* wob = (bf16*)alloc(WB);
    bf16* Qp  = (bf16*)alloc(SB);
    bf16* Kp  = (bf16*)alloc(SB);
    bf16* Vtp = (bf16*)alloc(SB);
    bf16* Ob  = (bf16*)alloc(SB);
    unsigned long long* maskb = (unsigned long long*)alloc(2048 * 32 * 8);

    cvt_kernel<<<dim3(2048, 1, 8), 256, 0, stream>>>(
        q, k, v, wq, wk, wv, wo, mask, qb, kb, vb, wqb, wkb, wvb, wob, maskb);

    gemm_kernel<0, 128><<<dim3(8, 32, 3), 256, 0, stream>>>(
        qb, kb, vb, wqb, wkb, wvb, Qp, Kp, Vtp, nullptr, nullptr);

    flash_kernel<<<dim3(16, 16, 2), 512, 0, stream>>>(Qp, Kp, Vtp, maskb, Ob);

    gemm_kernel<1, 64><<<dim3(8, 64, 1), 256, 0, stream>>>(
        Ob, nullptr, nullptr, wob, nullptr, nullptr,
        nullptr, nullptr, nullptr, bo, out);
}